// Round 3
// baseline (60.068 us; speedup 1.0000x reference)
//
#include <hip/hip_runtime.h>

// Chamfer distance, B=16, N=M=4096, fp32.
// dist(q,p) = |q|^2 + min_p(|p|^2 - 2 q.p)  -> 3 fma + 1 min per pair.
// R3: QPT=8 (32 VALU per ds_read_b128, LDS at 50%) AND 1024 blocks (4 waves/SIMD).
//     Needs NTC=16 chunks -> 8MB partial table; runtime-gated on ws_size.

#define BATCH 16
#define NPTS  4096
#define BLK   256                 // threads per block
#define QPT   8                   // queries per thread -> 2048 queries per block
#define QTILE (BLK * QPT)
#define NQT   (NPTS / QTILE)      // 2 query tiles per batch
#define NQ_TOTAL (BATCH * NPTS)   // 65536 queries per direction

template <int NTC>                // number of target chunks (8 or 16)
__global__ __launch_bounds__(BLK) void chamfer_partial_kernel(
    const float* __restrict__ xyz1, const float* __restrict__ xyz2,
    float* __restrict__ ws)
{
    constexpr int TCH = NPTS / NTC;     // targets per chunk (512 or 256)

    const int b   = blockIdx.x;         // batch
    const int qt  = blockIdx.y;         // query tile (0..NQT-1)
    const int zz  = blockIdx.z;         // tc (0..NTC-1) | dir*NTC
    const int tc  = zz % NTC;
    const int dir = zz / NTC;

    const float* __restrict__ qp = dir ? xyz2 : xyz1;
    const float* __restrict__ tp = dir ? xyz1 : xyz2;

    __shared__ float4 tgt[TCH + 1];     // +1 pad so rotating prefetch never branches

    // Stage target chunk into LDS as [x, y, z, |p|^2]
    const float* tbase = tp + ((size_t)b * NPTS + (size_t)tc * TCH) * 3;
    for (int i = threadIdx.x; i < TCH; i += BLK) {
        float x = tbase[i * 3 + 0];
        float y = tbase[i * 3 + 1];
        float z = tbase[i * 3 + 2];
        tgt[i] = make_float4(x, y, z, fmaf(x, x, fmaf(y, y, z * z)));
    }
    __syncthreads();

    // Load QPT query points into registers; precompute -2q and |q|^2.
    float m2x[QPT], m2y[QPT], m2z[QPT], qsq[QPT], acc[QPT];
    const float* qbase = qp + ((size_t)b * NPTS + (size_t)qt * QTILE) * 3;
    #pragma unroll
    for (int i = 0; i < QPT; ++i) {
        int qi = i * BLK + (int)threadIdx.x;
        float x = qbase[qi * 3 + 0];
        float y = qbase[qi * 3 + 1];
        float z = qbase[qi * 3 + 2];
        m2x[i] = -2.0f * x;
        m2y[i] = -2.0f * y;
        m2z[i] = -2.0f * z;
        qsq[i] = fmaf(x, x, fmaf(y, y, z * z));
        acc[i] = 1e30f;
    }

    // Main loop: rotating prefetch; 32 VALU insts per ds_read_b128.
    float4 p = tgt[0];
    #pragma unroll 4
    for (int t = 0; t < TCH; ++t) {
        float4 pn = tgt[t + 1];
        #pragma unroll
        for (int i = 0; i < QPT; ++i) {
            float d = fmaf(m2x[i], p.x, fmaf(m2y[i], p.y, fmaf(m2z[i], p.z, p.w)));
            acc[i] = fminf(acc[i], d);
        }
        p = pn;
    }

    // Write partial mins: ws[(dir*NTC + tc)][global_query]
    float* w = ws + ((size_t)(dir * NTC + tc)) * NQ_TOTAL;
    #pragma unroll
    for (int i = 0; i < QPT; ++i) {
        int q = b * NPTS + qt * QTILE + i * BLK + (int)threadIdx.x;
        float d = acc[i] + qsq[i];
        w[q] = d > 0.0f ? d : 0.0f;   // == min over clamped pair distances
    }
}

template <int NTC>
__global__ __launch_bounds__(BLK) void chamfer_reduce_kernel(
    const float* __restrict__ ws, float* __restrict__ out)
{
    // 2 * 65536 query-min values; j = dir*65536 + q
    const int j   = blockIdx.x * BLK + (int)threadIdx.x;   // grid covers exactly 131072
    const int dir = j >> 16;
    const int q   = j & (NQ_TOTAL - 1);

    const float* w = ws + (size_t)dir * NTC * NQ_TOTAL + q;
    float m = w[0];
    #pragma unroll
    for (int tc = 1; tc < NTC; ++tc) m = fminf(m, w[(size_t)tc * NQ_TOTAL]);

    float v = m * (1.0f / (float)NQ_TOTAL);   // mean contribution (N == M)

    // wave64 reduce
    #pragma unroll
    for (int off = 32; off >= 1; off >>= 1)
        v += __shfl_down(v, off, 64);

    __shared__ float wsum[BLK / 64];
    const int lane = (int)threadIdx.x & 63;
    const int wid  = (int)threadIdx.x >> 6;
    if (lane == 0) wsum[wid] = v;
    __syncthreads();
    if (threadIdx.x == 0) {
        float s = wsum[0] + wsum[1] + wsum[2] + wsum[3];
        atomicAdd(out, s);
    }
}

extern "C" void kernel_launch(void* const* d_in, const int* in_sizes, int n_in,
                              void* d_out, int out_size, void* d_ws, size_t ws_size,
                              hipStream_t stream) {
    const float* xyz1 = (const float*)d_in[0];
    const float* xyz2 = (const float*)d_in[1];
    float* out = (float*)d_out;
    float* ws  = (float*)d_ws;

    // zero the scalar accumulator (graph-capturable)
    hipMemsetAsync(out, 0, sizeof(float), stream);

    dim3 grid2((2 * NQ_TOTAL) / BLK);  // 512 blocks

    if (ws_size >= (size_t)2 * 16 * NQ_TOTAL * sizeof(float)) {
        // 16 chunks: grid 16 x 2 x 32 = 1024 blocks (4 waves/SIMD)
        dim3 grid1(BATCH, NQT, 16 * 2);
        chamfer_partial_kernel<16><<<grid1, BLK, 0, stream>>>(xyz1, xyz2, ws);
        chamfer_reduce_kernel<16><<<grid2, BLK, 0, stream>>>(ws, out);
    } else {
        // fallback: 8 chunks, 512 blocks (fits in 4MB ws)
        dim3 grid1(BATCH, NQT, 8 * 2);
        chamfer_partial_kernel<8><<<grid1, BLK, 0, stream>>>(xyz1, xyz2, ws);
        chamfer_reduce_kernel<8><<<grid2, BLK, 0, stream>>>(ws, out);
    }
}

// Round 4
// 49.757 us; speedup vs baseline: 1.2072x; 1.2072x over previous
//
#include <hip/hip_runtime.h>

// Chamfer distance via MFMA, B=16, N=M=4096, fp32 in/out.
// E(q,p) = |q|^2 + F(q,p),  F = |p|^2 - 2 q.p  computed by mfma_f32_32x32x16_bf16
// with hi/lo bf16 splits (3-term Dekker per coordinate, hi/lo for |p|^2):
//   a_arr(q) = [xh,xh,xl, yh,yh,yl, zh,zh | zl, 1, 1, 0,0,0,0,0]   (x* = split(-2qx))
//   b_arr(p) = [Xh,Xl,Xh, Yh,Yl,Yh, Zh,Zl | Zh, Sh, Sl, 0,0,0,0,0] (X* = split(px), S=|p|^2)
// k0..k10 products sum to F exactly up to ~2^-18 relative terms.
// |q|^2 added in fp32 at reduce time; clamp(>=0) matches jnp.maximum(d,0).

#define BATCH 16
#define NPTS  4096
#define NQ_TOTAL (BATCH * NPTS)   // 65536 per direction
#define TILES 128                 // NPTS / 32 target tiles
#define STRIPS 128                // NPTS / 32 query strips

typedef __attribute__((ext_vector_type(8)))  short bf16x8;
typedef __attribute__((ext_vector_type(16))) float f32x16;
typedef __attribute__((ext_vector_type(4)))  unsigned int u32x4;

union FragCast { bf16x8 v; u32x4 u; };

__device__ __forceinline__ unsigned short bf16_rne(float v) {
    unsigned u = __float_as_uint(v);
    u += 0x7FFFu + ((u >> 16) & 1u);          // round-to-nearest-even
    return (unsigned short)(u >> 16);
}
__device__ __forceinline__ float bf16f(unsigned short h) {
    return __uint_as_float(((unsigned)h) << 16);
}

// ---------------- Pass 1: pack B-role fragments for both point sets ----------
// frags[set][b][tile][lane] : 16 bytes (8 bf16 = the lane's contiguous k-chunk)
__global__ __launch_bounds__(256) void pack_kernel(
    const float* __restrict__ xyz1, const float* __restrict__ xyz2,
    u32x4* __restrict__ frags, float* __restrict__ sq)
{
    const int wid = (int)threadIdx.x >> 6;
    const int l   = (int)threadIdx.x & 63;
    const int c   = l & 31;          // point within tile
    const int g   = l >> 5;          // k-chunk group
    const int tt  = blockIdx.x * 4 + wid;
    const int b   = blockIdx.y;
    const int s   = blockIdx.z;      // point set

    const float* pts = s ? xyz2 : xyz1;
    const int idx = b * NPTS + tt * 32 + c;
    const float x = pts[idx * 3 + 0];
    const float y = pts[idx * 3 + 1];
    const float z = pts[idx * 3 + 2];
    const float S = fmaf(x, x, fmaf(y, y, z * z));

    const unsigned short Xh = bf16_rne(x), Xl = bf16_rne(x - bf16f(Xh));
    const unsigned short Yh = bf16_rne(y), Yl = bf16_rne(y - bf16f(Yh));
    const unsigned short Zh = bf16_rne(z), Zl = bf16_rne(z - bf16f(Zh));
    const unsigned short Sh = bf16_rne(S), Sl = bf16_rne(S - bf16f(Sh));

    FragCast fc;
    if (g == 0) {
        fc.v[0] = (short)Xh; fc.v[1] = (short)Xl; fc.v[2] = (short)Xh; fc.v[3] = (short)Yh;
        fc.v[4] = (short)Yl; fc.v[5] = (short)Yh; fc.v[6] = (short)Zh; fc.v[7] = (short)Zl;
    } else {
        fc.v[0] = (short)Zh; fc.v[1] = (short)Sh; fc.v[2] = (short)Sl; fc.v[3] = 0;
        fc.v[4] = 0;         fc.v[5] = 0;         fc.v[6] = 0;         fc.v[7] = 0;
    }
    frags[(((size_t)s * BATCH + b) * TILES + tt) * 64 + l] = fc.u;
    if (g == 0) sq[s * NQ_TOTAL + idx] = S;
}

// ---------------- Pass 2: MFMA pair-distance + row-min ----------------------
__global__ __launch_bounds__(256) void chamfer_mfma_kernel(
    const float* __restrict__ xyz1, const float* __restrict__ xyz2,
    const u32x4* __restrict__ frags, float* __restrict__ rowmin)
{
    // XCD-locality swizzle: 1024 blocks -> each XCD owns 4 (batch,dir) combos
    const int orig = (int)blockIdx.x + 32 * ((int)blockIdx.y + 16 * (int)blockIdx.z);
    const int wfid = (orig & 7) * 128 + (orig >> 3);
    const int sg = wfid & 31;          // strip group (4 strips)
    const int b  = (wfid >> 5) & 15;   // batch
    const int d  = wfid >> 9;          // direction

    const int wid = (int)threadIdx.x >> 6;
    const int l   = (int)threadIdx.x & 63;
    const int c   = l & 31;
    const int g   = l >> 5;
    const int strip = sg * 4 + wid;

    // Build A-role fragment (query = row c of this strip) in registers.
    const float* qpts = d ? xyz2 : xyz1;
    const int qi = b * NPTS + strip * 32 + c;
    const float mx = -2.0f * qpts[qi * 3 + 0];
    const float my = -2.0f * qpts[qi * 3 + 1];
    const float mz = -2.0f * qpts[qi * 3 + 2];
    const unsigned short xh = bf16_rne(mx), xl = bf16_rne(mx - bf16f(xh));
    const unsigned short yh = bf16_rne(my), yl = bf16_rne(my - bf16f(yh));
    const unsigned short zh = bf16_rne(mz), zl = bf16_rne(mz - bf16f(zh));
    const unsigned short one = 0x3F80;   // bf16(1.0)

    bf16x8 af;
    if (g == 0) {
        af[0] = (short)xh; af[1] = (short)xh; af[2] = (short)xl; af[3] = (short)yh;
        af[4] = (short)yh; af[5] = (short)yl; af[6] = (short)zh; af[7] = (short)zh;
    } else {
        af[0] = (short)zl; af[1] = (short)one; af[2] = (short)one; af[3] = 0;
        af[4] = 0;         af[5] = 0;          af[6] = 0;          af[7] = 0;
    }

    f32x16 vzero;
    #pragma unroll
    for (int i = 0; i < 16; ++i) vzero[i] = 0.0f;

    f32x16 rm;
    #pragma unroll
    for (int i = 0; i < 16; ++i) rm[i] = 1e30f;

    __shared__ u32x4 lds[32 * 64];   // 32 tiles x 64 lanes x 16B = 32 KiB

    const u32x4* gf = frags + (((size_t)(1 - d) * BATCH + b) * TILES) * 64;

    for (int cc = 0; cc < 4; ++cc) {           // 4 chunks x 32 tiles = 128 tiles
        __syncthreads();
        const u32x4* src = gf + cc * (32 * 64);
        #pragma unroll
        for (int i = 0; i < 8; ++i)
            lds[i * 256 + threadIdx.x] = src[i * 256 + threadIdx.x];
        __syncthreads();

        #pragma unroll 2
        for (int t = 0; t < 32; t += 2) {
            FragCast ta, tb;
            ta.u = lds[(t + 0) * 64 + l];
            tb.u = lds[(t + 1) * 64 + l];
            f32x16 aA = __builtin_amdgcn_mfma_f32_32x32x16_bf16(af, ta.v, vzero, 0, 0, 0);
            f32x16 aB = __builtin_amdgcn_mfma_f32_32x32x16_bf16(af, tb.v, vzero, 0, 0, 0);
            #pragma unroll
            for (int i = 0; i < 16; ++i)
                rm[i] = fminf(fminf(rm[i], aA[i]), aB[i]);   // -> v_min3_f32
        }
    }

    // Cross-lane min over the 32 columns (lanes within each 32-lane half).
    #pragma unroll
    for (int m = 1; m <= 16; m <<= 1) {
        #pragma unroll
        for (int i = 0; i < 16; ++i)
            rm[i] = fminf(rm[i], __shfl_xor(rm[i], m, 64));
    }

    // C layout (m74/m101): col = lane&31, row = (reg&3) + 8*(reg>>2) + 4*(lane>>5)
    if (c == 0) {
        float* outp = rowmin + (size_t)d * NQ_TOTAL + b * NPTS + strip * 32 + 4 * g;
        #pragma unroll
        for (int i = 0; i < 16; ++i)
            outp[(i & 3) + 8 * (i >> 2)] = rm[i];
    }
}

// ---------------- Pass 3: add |q|^2, clamp, mean, atomic accumulate ---------
__global__ __launch_bounds__(256) void reduce_kernel(
    const float* __restrict__ rowmin, const float* __restrict__ sq,
    float* __restrict__ out)
{
    const int j = (int)blockIdx.x * 256 + (int)threadIdx.x;   // 0..131071
    float v = fmaxf(rowmin[j] + sq[j], 0.0f) * (1.0f / (float)NQ_TOTAL);

    #pragma unroll
    for (int off = 32; off >= 1; off >>= 1)
        v += __shfl_down(v, off, 64);

    __shared__ float wsum[4];
    const int lane = (int)threadIdx.x & 63;
    const int wid  = (int)threadIdx.x >> 6;
    if (lane == 0) wsum[wid] = v;
    __syncthreads();
    if (threadIdx.x == 0)
        atomicAdd(out, wsum[0] + wsum[1] + wsum[2] + wsum[3]);
}

extern "C" void kernel_launch(void* const* d_in, const int* in_sizes, int n_in,
                              void* d_out, int out_size, void* d_ws, size_t ws_size,
                              hipStream_t stream) {
    const float* xyz1 = (const float*)d_in[0];
    const float* xyz2 = (const float*)d_in[1];
    float* out = (float*)d_out;

    // ws layout: [0,4MB) frags | [4MB,4.5MB) sq | [4.5MB,5MB) rowmin
    u32x4* frags  = (u32x4*)d_ws;
    float* sq     = (float*)((char*)d_ws + (4u << 20));
    float* rowmin = (float*)((char*)d_ws + (4u << 20) + (512u << 10));

    hipMemsetAsync(out, 0, sizeof(float), stream);

    dim3 gridP(32, BATCH, 2);   // 1024 blocks: tiles/4 x batch x set
    pack_kernel<<<gridP, 256, 0, stream>>>(xyz1, xyz2, frags, sq);

    dim3 gridM(32, BATCH, 2);   // 1024 blocks: strip-group x batch x dir
    chamfer_mfma_kernel<<<gridM, 256, 0, stream>>>(xyz1, xyz2, frags, rowmin);

    reduce_kernel<<<(2 * NQ_TOTAL) / 256, 256, 0, stream>>>(rowmin, sq, out);
}

// Round 5
// 39.419 us; speedup vs baseline: 1.5238x; 1.2623x over previous
//
#include <hip/hip_runtime.h>

// Chamfer distance via MFMA, B=16, N=M=4096, fp32 in/out.
// d(q,p) = |q|^2 - 2 q.p + |p|^2 computed ENTIRELY by mfma_f32_32x32x16_bf16
// with hi/lo bf16 splits (3-term Dekker per coordinate, hi/lo for |p|^2,|q|^2):
//   k0..k8  : 3 products per coordinate of (-2q).p
//   k9,k10  : 1*Sh + 1*Sl        (S = |p|^2)
//   k11,k12 : Qh*1 + Ql*1        (Q = |q|^2)
// MFMA output = full squared distance; per-strip row-min -> clamp -> block
// partial sum -> single-block final reduce. No memset, no atomics.

#define BATCH 16
#define NPTS  4096
#define NQ_TOTAL (BATCH * NPTS)   // 65536 per direction
#define TILES 128                 // NPTS / 32

typedef __attribute__((ext_vector_type(8)))  short bf16x8;
typedef __attribute__((ext_vector_type(16))) float f32x16;
typedef __attribute__((ext_vector_type(4)))  unsigned int u32x4;

union FragCast { bf16x8 v; u32x4 u; };

__device__ __forceinline__ unsigned short bf16_rne(float v) {
    unsigned u = __float_as_uint(v);
    u += 0x7FFFu + ((u >> 16) & 1u);          // round-to-nearest-even
    return (unsigned short)(u >> 16);
}
__device__ __forceinline__ float bf16f(unsigned short h) {
    return __uint_as_float(((unsigned)h) << 16);
}

// ---------------- Pass 1: pack B-role fragments for both point sets ----------
// frags[set][b][tile][lane] : 16 bytes (8 bf16 = the lane's contiguous k-chunk)
__global__ __launch_bounds__(256) void pack_kernel(
    const float* __restrict__ xyz1, const float* __restrict__ xyz2,
    u32x4* __restrict__ frags)
{
    const int wid = (int)threadIdx.x >> 6;
    const int l   = (int)threadIdx.x & 63;
    const int c   = l & 31;          // point within tile
    const int g   = l >> 5;          // k-chunk group
    const int tt  = blockIdx.x * 4 + wid;
    const int b   = blockIdx.y;
    const int s   = blockIdx.z;      // point set

    const float* pts = s ? xyz2 : xyz1;
    const int idx = b * NPTS + tt * 32 + c;
    const float x = pts[idx * 3 + 0];
    const float y = pts[idx * 3 + 1];
    const float z = pts[idx * 3 + 2];
    const float S = fmaf(x, x, fmaf(y, y, z * z));

    const unsigned short Xh = bf16_rne(x), Xl = bf16_rne(x - bf16f(Xh));
    const unsigned short Yh = bf16_rne(y), Yl = bf16_rne(y - bf16f(Yh));
    const unsigned short Zh = bf16_rne(z), Zl = bf16_rne(z - bf16f(Zh));
    const unsigned short Sh = bf16_rne(S), Sl = bf16_rne(S - bf16f(Sh));
    const unsigned short one = 0x3F80;   // bf16(1.0)

    FragCast fc;
    if (g == 0) {
        fc.v[0] = (short)Xh; fc.v[1] = (short)Xl; fc.v[2] = (short)Xh; fc.v[3] = (short)Yh;
        fc.v[4] = (short)Yl; fc.v[5] = (short)Yh; fc.v[6] = (short)Zh; fc.v[7] = (short)Zl;
    } else {
        fc.v[0] = (short)Zh; fc.v[1] = (short)Sh; fc.v[2] = (short)Sl; fc.v[3] = (short)one;
        fc.v[4] = (short)one; fc.v[5] = 0;        fc.v[6] = 0;         fc.v[7] = 0;
    }
    frags[(((size_t)s * BATCH + b) * TILES + tt) * 64 + l] = fc.u;
}

// ---------------- Pass 2: MFMA pair-distance + row-min + block partial sum --
__global__ __launch_bounds__(256) void chamfer_mfma_kernel(
    const float* __restrict__ xyz1, const float* __restrict__ xyz2,
    const u32x4* __restrict__ frags, float* __restrict__ partials)
{
    // XCD-locality swizzle: 1024 blocks -> each XCD owns 4 (batch,dir) combos
    const int orig = (int)blockIdx.x + 32 * ((int)blockIdx.y + 16 * (int)blockIdx.z);
    const int wfid = (orig & 7) * 128 + (orig >> 3);
    const int sg = wfid & 31;          // strip group (4 strips)
    const int b  = (wfid >> 5) & 15;   // batch
    const int d  = wfid >> 9;          // direction

    const int wid = (int)threadIdx.x >> 6;
    const int l   = (int)threadIdx.x & 63;
    const int c   = l & 31;
    const int g   = l >> 5;
    const int strip = sg * 4 + wid;

    // Build A-role fragment (query = row c of this strip) in registers.
    const float* qpts = d ? xyz2 : xyz1;
    const int qi = b * NPTS + strip * 32 + c;
    const float qx = qpts[qi * 3 + 0];
    const float qy = qpts[qi * 3 + 1];
    const float qz = qpts[qi * 3 + 2];
    const float mx = -2.0f * qx, my = -2.0f * qy, mz = -2.0f * qz;
    const float Q  = fmaf(qx, qx, fmaf(qy, qy, qz * qz));
    const unsigned short xh = bf16_rne(mx), xl = bf16_rne(mx - bf16f(xh));
    const unsigned short yh = bf16_rne(my), yl = bf16_rne(my - bf16f(yh));
    const unsigned short zh = bf16_rne(mz), zl = bf16_rne(mz - bf16f(zh));
    const unsigned short Qh = bf16_rne(Q),  Ql = bf16_rne(Q - bf16f(Qh));
    const unsigned short one = 0x3F80;   // bf16(1.0)

    bf16x8 af;
    if (g == 0) {
        af[0] = (short)xh; af[1] = (short)xh; af[2] = (short)xl; af[3] = (short)yh;
        af[4] = (short)yh; af[5] = (short)yl; af[6] = (short)zh; af[7] = (short)zh;
    } else {
        af[0] = (short)zl; af[1] = (short)one; af[2] = (short)one; af[3] = (short)Qh;
        af[4] = (short)Ql; af[5] = 0;          af[6] = 0;          af[7] = 0;
    }

    f32x16 vzero;
    #pragma unroll
    for (int i = 0; i < 16; ++i) vzero[i] = 0.0f;

    f32x16 rm;
    #pragma unroll
    for (int i = 0; i < 16; ++i) rm[i] = 1e30f;

    __shared__ u32x4 lds[32 * 64];   // 32 tiles x 64 lanes x 16B = 32 KiB

    const u32x4* gf = frags + (((size_t)(1 - d) * BATCH + b) * TILES) * 64;

    for (int cc = 0; cc < 4; ++cc) {           // 4 chunks x 32 tiles = 128 tiles
        __syncthreads();
        const u32x4* src = gf + cc * (32 * 64);
        #pragma unroll
        for (int i = 0; i < 8; ++i)
            lds[i * 256 + threadIdx.x] = src[i * 256 + threadIdx.x];
        __syncthreads();

        #pragma unroll 2
        for (int t = 0; t < 32; t += 2) {
            FragCast ta, tb;
            ta.u = lds[(t + 0) * 64 + l];
            tb.u = lds[(t + 1) * 64 + l];
            f32x16 aA = __builtin_amdgcn_mfma_f32_32x32x16_bf16(af, ta.v, vzero, 0, 0, 0);
            f32x16 aB = __builtin_amdgcn_mfma_f32_32x32x16_bf16(af, tb.v, vzero, 0, 0, 0);
            #pragma unroll
            for (int i = 0; i < 16; ++i)
                rm[i] = fminf(fminf(rm[i], aA[i]), aB[i]);   // -> v_min3_f32
        }
    }

    // Cross-lane min over the 32 columns (within each 32-lane half; the two
    // halves hold disjoint row sets per the C layout row=(i&3)+8*(i>>2)+4*g).
    #pragma unroll
    for (int m = 1; m <= 16; m <<= 1) {
        #pragma unroll
        for (int i = 0; i < 16; ++i)
            rm[i] = fminf(rm[i], __shfl_xor(rm[i], m, 64));
    }

    // rm[i] is now the COMPLETE min over all 4096 targets for row (i&3)+8*(i>>2)+4*g.
    // Clamp (matches jnp.maximum(d,0); min of clamped == clamp of min) and sum.
    float s = 0.0f;
    #pragma unroll
    for (int i = 0; i < 16; ++i) s += fmaxf(rm[i], 0.0f);
    s += __shfl_xor(s, 32, 64);      // combine the two row-halves -> strip total

    __shared__ float wsum[4];
    if (l == 0) wsum[wid] = s;
    __syncthreads();
    if (threadIdx.x == 0)
        partials[orig] = wsum[0] + wsum[1] + wsum[2] + wsum[3];
}

// ---------------- Pass 3: single-block final sum -> mean -------------------
__global__ __launch_bounds__(256) void final_kernel(
    const float* __restrict__ partials, float* __restrict__ out)
{
    const int t = (int)threadIdx.x;
    float v = partials[t] + partials[t + 256] + partials[t + 512] + partials[t + 768];

    #pragma unroll
    for (int off = 32; off >= 1; off >>= 1)
        v += __shfl_down(v, off, 64);

    __shared__ float wsum[4];
    const int lane = t & 63;
    const int wid  = t >> 6;
    if (lane == 0) wsum[wid] = v;
    __syncthreads();
    if (t == 0)
        out[0] = (wsum[0] + wsum[1] + wsum[2] + wsum[3]) * (1.0f / (float)NQ_TOTAL);
}

extern "C" void kernel_launch(void* const* d_in, const int* in_sizes, int n_in,
                              void* d_out, int out_size, void* d_ws, size_t ws_size,
                              hipStream_t stream) {
    const float* xyz1 = (const float*)d_in[0];
    const float* xyz2 = (const float*)d_in[1];
    float* out = (float*)d_out;

    // ws layout: [0,4MB) frags | [4MB, 4MB+4KB) block partials
    u32x4* frags    = (u32x4*)d_ws;
    float* partials = (float*)((char*)d_ws + (4u << 20));

    dim3 gridP(32, BATCH, 2);   // 1024 blocks: tiles/4 x batch x set
    pack_kernel<<<gridP, 256, 0, stream>>>(xyz1, xyz2, frags);

    dim3 gridM(32, BATCH, 2);   // 1024 blocks: strip-group x batch x dir
    chamfer_mfma_kernel<<<gridM, 256, 0, stream>>>(xyz1, xyz2, frags, partials);

    final_kernel<<<1, 256, 0, stream>>>(partials, out);
}

// Round 6
// 31.603 us; speedup vs baseline: 1.9007x; 1.2473x over previous
//
#include <hip/hip_runtime.h>

// Chamfer distance via MFMA, B=16, N=M=4096, fp32 in/out.
// d(q,p) = |q|^2 - 2 q.p + |p|^2 entirely inside mfma_f32_32x32x16_bf16 via
// hi/lo bf16 splits (k0..k8: Dekker products of (-2q).p; k9,k10: |p|^2 hi/lo;
// k11,k12: |q|^2 hi/lo). Row-min -> clamp -> partial sums -> final reduce.
// R6: 2 query strips per wave, 2 tiles per iteration -> 1 ds_read_b128 feeds
//     2 MFMAs; 64KB LDS chunks; 512 blocks (2/CU).

#define BATCH 16
#define NPTS  4096
#define NQ_TOTAL (BATCH * NPTS)   // 65536 per direction
#define TILES 128                 // NPTS / 32

typedef __attribute__((ext_vector_type(8)))  short bf16x8;
typedef __attribute__((ext_vector_type(16))) float f32x16;
typedef __attribute__((ext_vector_type(4)))  unsigned int u32x4;

union FragCast { bf16x8 v; u32x4 u; };

__device__ __forceinline__ unsigned short bf16_rne(float v) {
    unsigned u = __float_as_uint(v);
    u += 0x7FFFu + ((u >> 16) & 1u);          // round-to-nearest-even
    return (unsigned short)(u >> 16);
}
__device__ __forceinline__ float bf16f(unsigned short h) {
    return __uint_as_float(((unsigned)h) << 16);
}

// ---------------- Pass 1: pack B-role fragments for both point sets ----------
// frags[set][b][tile][lane] : 16 bytes (8 bf16 = the lane's contiguous k-chunk)
__global__ __launch_bounds__(256) void pack_kernel(
    const float* __restrict__ xyz1, const float* __restrict__ xyz2,
    u32x4* __restrict__ frags)
{
    const int wid = (int)threadIdx.x >> 6;
    const int l   = (int)threadIdx.x & 63;
    const int c   = l & 31;          // point within tile
    const int g   = l >> 5;          // k-chunk group
    const int tt  = blockIdx.x * 4 + wid;
    const int b   = blockIdx.y;
    const int s   = blockIdx.z;      // point set

    const float* pts = s ? xyz2 : xyz1;
    const int idx = b * NPTS + tt * 32 + c;
    const float x = pts[idx * 3 + 0];
    const float y = pts[idx * 3 + 1];
    const float z = pts[idx * 3 + 2];
    const float S = fmaf(x, x, fmaf(y, y, z * z));

    const unsigned short Xh = bf16_rne(x), Xl = bf16_rne(x - bf16f(Xh));
    const unsigned short Yh = bf16_rne(y), Yl = bf16_rne(y - bf16f(Yh));
    const unsigned short Zh = bf16_rne(z), Zl = bf16_rne(z - bf16f(Zh));
    const unsigned short Sh = bf16_rne(S), Sl = bf16_rne(S - bf16f(Sh));
    const unsigned short one = 0x3F80;   // bf16(1.0)

    FragCast fc;
    if (g == 0) {
        fc.v[0] = (short)Xh; fc.v[1] = (short)Xl; fc.v[2] = (short)Xh; fc.v[3] = (short)Yh;
        fc.v[4] = (short)Yl; fc.v[5] = (short)Yh; fc.v[6] = (short)Zh; fc.v[7] = (short)Zl;
    } else {
        fc.v[0] = (short)Zh; fc.v[1] = (short)Sh; fc.v[2] = (short)Sl; fc.v[3] = (short)one;
        fc.v[4] = (short)one; fc.v[5] = 0;        fc.v[6] = 0;         fc.v[7] = 0;
    }
    frags[(((size_t)s * BATCH + b) * TILES + tt) * 64 + l] = fc.u;
}

// ---------------- Pass 2: MFMA pair-distance, 2 strips/wave -----------------
__global__ __launch_bounds__(256, 2) void chamfer_mfma_kernel(
    const float* __restrict__ xyz1, const float* __restrict__ xyz2,
    const u32x4* __restrict__ frags, float* __restrict__ partials)
{
    // 512 blocks; XCD swizzle (512 % 8 == 0, bijective): each XCD's 64 blocks
    // cover 4 contiguous (b,d) pairs -> 4 x 128KB frag slices in its L2.
    const int orig = (int)blockIdx.x;
    const int wfid = (orig & 7) * 64 + (orig >> 3);
    const int og = wfid & 15;          // strip octet (8 strips)
    const int b  = (wfid >> 4) & 15;   // batch
    const int d  = wfid >> 8;          // direction

    const int wid = (int)threadIdx.x >> 6;
    const int l   = (int)threadIdx.x & 63;
    const int c   = l & 31;
    const int g   = l >> 5;
    const int strip0 = og * 8 + wid;       // this wave's two query strips
    const int strip1 = og * 8 + wid + 4;

    // Build the two A-role fragments in registers.
    const float* qpts = d ? xyz2 : xyz1;
    const unsigned short one = 0x3F80;
    bf16x8 af0, af1;
    #pragma unroll
    for (int s = 0; s < 2; ++s) {
        const int strip = s ? strip1 : strip0;
        const int qi = b * NPTS + strip * 32 + c;
        const float qx = qpts[qi * 3 + 0];
        const float qy = qpts[qi * 3 + 1];
        const float qz = qpts[qi * 3 + 2];
        const float mx = -2.0f * qx, my = -2.0f * qy, mz = -2.0f * qz;
        const float Q  = fmaf(qx, qx, fmaf(qy, qy, qz * qz));
        const unsigned short xh = bf16_rne(mx), xl = bf16_rne(mx - bf16f(xh));
        const unsigned short yh = bf16_rne(my), yl = bf16_rne(my - bf16f(yh));
        const unsigned short zh = bf16_rne(mz), zl = bf16_rne(mz - bf16f(zh));
        const unsigned short Qh = bf16_rne(Q),  Ql = bf16_rne(Q - bf16f(Qh));
        bf16x8 af;
        if (g == 0) {
            af[0] = (short)xh; af[1] = (short)xh; af[2] = (short)xl; af[3] = (short)yh;
            af[4] = (short)yh; af[5] = (short)yl; af[6] = (short)zh; af[7] = (short)zh;
        } else {
            af[0] = (short)zl; af[1] = (short)one; af[2] = (short)one; af[3] = (short)Qh;
            af[4] = (short)Ql; af[5] = 0;          af[6] = 0;          af[7] = 0;
        }
        if (s) af1 = af; else af0 = af;
    }

    f32x16 vzero;
    #pragma unroll
    for (int i = 0; i < 16; ++i) vzero[i] = 0.0f;

    f32x16 rm0, rm1;
    #pragma unroll
    for (int i = 0; i < 16; ++i) { rm0[i] = 1e30f; rm1[i] = 1e30f; }

    __shared__ u32x4 lds[64 * 64];   // 64 tiles x 64 lanes x 16B = 64 KiB

    const u32x4* gf = frags + (((size_t)(1 - d) * BATCH + b) * TILES) * 64;

    for (int cc = 0; cc < 2; ++cc) {           // 2 chunks x 64 tiles
        __syncthreads();
        const u32x4* src = gf + cc * (64 * 64);
        #pragma unroll
        for (int i = 0; i < 16; ++i)
            lds[i * 256 + threadIdx.x] = src[i * 256 + threadIdx.x];
        __syncthreads();

        #pragma unroll 2
        for (int t = 0; t < 64; t += 2) {
            FragCast ta, tb;
            ta.u = lds[(t + 0) * 64 + l];
            tb.u = lds[(t + 1) * 64 + l];
            // 1 ds_read pair feeds 4 MFMAs (2 strips x 2 tiles)
            f32x16 a0 = __builtin_amdgcn_mfma_f32_32x32x16_bf16(af0, ta.v, vzero, 0, 0, 0);
            f32x16 a1 = __builtin_amdgcn_mfma_f32_32x32x16_bf16(af0, tb.v, vzero, 0, 0, 0);
            f32x16 b0 = __builtin_amdgcn_mfma_f32_32x32x16_bf16(af1, ta.v, vzero, 0, 0, 0);
            f32x16 b1 = __builtin_amdgcn_mfma_f32_32x32x16_bf16(af1, tb.v, vzero, 0, 0, 0);
            #pragma unroll
            for (int i = 0; i < 16; ++i) {
                rm0[i] = fminf(fminf(rm0[i], a0[i]), a1[i]);   // -> v_min3_f32
                rm1[i] = fminf(fminf(rm1[i], b0[i]), b1[i]);
            }
        }
    }

    // Cross-lane min over the 32 columns (within each 32-lane half; halves
    // hold disjoint row sets per C layout row=(i&3)+8*(i>>2)+4*g).
    #pragma unroll
    for (int m = 1; m <= 16; m <<= 1) {
        #pragma unroll
        for (int i = 0; i < 16; ++i) {
            rm0[i] = fminf(rm0[i], __shfl_xor(rm0[i], m, 64));
            rm1[i] = fminf(rm1[i], __shfl_xor(rm1[i], m, 64));
        }
    }

    // Clamp (min of clamped == clamp of min) and sum this wave's 64 rows.
    float s0 = 0.0f, s1 = 0.0f;
    #pragma unroll
    for (int i = 0; i < 16; ++i) {
        s0 += fmaxf(rm0[i], 0.0f);
        s1 += fmaxf(rm1[i], 0.0f);
    }
    s0 += __shfl_xor(s0, 32, 64);    // combine the two row-halves of strip0
    s1 += __shfl_xor(s1, 32, 64);    // ... strip1
    const float s = s0 + s1;

    __shared__ float wsum[4];
    if (l == 0) wsum[wid] = s;
    __syncthreads();
    if (threadIdx.x == 0)
        partials[orig] = wsum[0] + wsum[1] + wsum[2] + wsum[3];
}

// ---------------- Pass 3: single-block final sum -> mean -------------------
__global__ __launch_bounds__(256) void final_kernel(
    const float* __restrict__ partials, float* __restrict__ out)
{
    const int t = (int)threadIdx.x;
    float v = partials[t] + partials[t + 256];

    #pragma unroll
    for (int off = 32; off >= 1; off >>= 1)
        v += __shfl_down(v, off, 64);

    __shared__ float wsum[4];
    const int lane = t & 63;
    const int wid  = t >> 6;
    if (lane == 0) wsum[wid] = v;
    __syncthreads();
    if (t == 0)
        out[0] = (wsum[0] + wsum[1] + wsum[2] + wsum[3]) * (1.0f / (float)NQ_TOTAL);
}

extern "C" void kernel_launch(void* const* d_in, const int* in_sizes, int n_in,
                              void* d_out, int out_size, void* d_ws, size_t ws_size,
                              hipStream_t stream) {
    const float* xyz1 = (const float*)d_in[0];
    const float* xyz2 = (const float*)d_in[1];
    float* out = (float*)d_out;

    // ws layout: [0,4MB) frags | [4MB, 4MB+2KB) block partials
    u32x4* frags    = (u32x4*)d_ws;
    float* partials = (float*)((char*)d_ws + (4u << 20));

    dim3 gridP(32, BATCH, 2);   // 1024 blocks: tiles/4 x batch x set
    pack_kernel<<<gridP, 256, 0, stream>>>(xyz1, xyz2, frags);

    chamfer_mfma_kernel<<<512, 256, 0, stream>>>(xyz1, xyz2, frags, partials);

    final_kernel<<<1, 256, 0, stream>>>(partials, out);
}

// Round 8
// 27.077 us; speedup vs baseline: 2.2184x; 1.1671x over previous
//
#include <hip/hip_runtime.h>

// Chamfer distance via MFMA, B=16, N=M=4096, fp32 in/out. Two dispatches:
//   1) fused main: self-pack target tiles into LDS -> mfma pair-distance ->
//      row-min -> clamp -> block partial sums
//   2) final: 1-block sum of 512 partials -> mean -> out[0]
// d(q,p) = |q|^2 - 2 q.p + |p|^2 inside mfma_f32_32x32x16_bf16 via hi/lo bf16
// splits (k0..k8: Dekker products of (-2q).p; k9,k10: |p|^2; k11,k12: |q|^2).

#define BATCH 16
#define NPTS  4096
#define NQ_TOTAL (BATCH * NPTS)   // 65536 per direction

typedef __attribute__((ext_vector_type(8)))  short bf16x8;
typedef __attribute__((ext_vector_type(16))) float f32x16;
typedef __attribute__((ext_vector_type(4)))  unsigned int u32x4;

union FragCast { bf16x8 v; u32x4 u; };

__device__ __forceinline__ unsigned short bf16_rne(float v) {
    unsigned u = __float_as_uint(v);
    u += 0x7FFFu + ((u >> 16) & 1u);          // round-to-nearest-even
    return (unsigned short)(u >> 16);
}
__device__ __forceinline__ float bf16f(unsigned short h) {
    return __uint_as_float(((unsigned)h) << 16);
}

__global__ __launch_bounds__(256, 2) void chamfer_fused_kernel(
    const float* __restrict__ xyz1, const float* __restrict__ xyz2,
    float* __restrict__ partials)
{
    // 512 blocks; XCD swizzle (512 % 8 == 0, bijective): each XCD's 64 blocks
    // cover 4 contiguous (b,d) pairs -> their xyz slices live in its L2.
    const int orig = (int)blockIdx.x;
    const int wfid = (orig & 7) * 64 + (orig >> 3);
    const int og = wfid & 15;          // strip octet (8 strips)
    const int b  = (wfid >> 4) & 15;   // batch
    const int d  = wfid >> 8;          // direction

    const int tid = (int)threadIdx.x;
    const int wid = tid >> 6;
    const int l   = tid & 63;
    const int c   = l & 31;
    const int g   = l >> 5;
    const int strip0 = og * 8 + wid;       // this wave's two query strips
    const int strip1 = og * 8 + wid + 4;

    const float* qpts = d ? xyz2 : xyz1;   // queries: set d
    const float* tpts = d ? xyz1 : xyz2;   // targets: set 1-d

    // ---- Build the two A-role fragments in registers (same as R6) ----
    const unsigned short one = 0x3F80;
    bf16x8 af0, af1;
    #pragma unroll
    for (int s = 0; s < 2; ++s) {
        const int strip = s ? strip1 : strip0;
        const int qi = b * NPTS + strip * 32 + c;
        const float qx = qpts[qi * 3 + 0];
        const float qy = qpts[qi * 3 + 1];
        const float qz = qpts[qi * 3 + 2];
        const float mx = -2.0f * qx, my = -2.0f * qy, mz = -2.0f * qz;
        const float Q  = fmaf(qx, qx, fmaf(qy, qy, qz * qz));
        const unsigned short xh = bf16_rne(mx), xl = bf16_rne(mx - bf16f(xh));
        const unsigned short yh = bf16_rne(my), yl = bf16_rne(my - bf16f(yh));
        const unsigned short zh = bf16_rne(mz), zl = bf16_rne(mz - bf16f(zh));
        const unsigned short Qh = bf16_rne(Q),  Ql = bf16_rne(Q - bf16f(Qh));
        bf16x8 af;
        if (g == 0) {
            af[0] = (short)xh; af[1] = (short)xh; af[2] = (short)xl; af[3] = (short)yh;
            af[4] = (short)yh; af[5] = (short)yl; af[6] = (short)zh; af[7] = (short)zh;
        } else {
            af[0] = (short)zl; af[1] = (short)one; af[2] = (short)one; af[3] = (short)Qh;
            af[4] = (short)Ql; af[5] = 0;          af[6] = 0;          af[7] = 0;
        }
        if (s) af1 = af; else af0 = af;
    }

    f32x16 vzero;
    #pragma unroll
    for (int i = 0; i < 16; ++i) vzero[i] = 0.0f;

    f32x16 rm0, rm1;
    #pragma unroll
    for (int i = 0; i < 16; ++i) { rm0[i] = 1e30f; rm1[i] = 1e30f; }

    __shared__ u32x4 lds[64 * 64];   // 64 tiles x 64 lanes x 16B = 64 KiB

    for (int cc = 0; cc < 2; ++cc) {           // 2 chunks x 64 tiles
        __syncthreads();

        // ---- Self-pack chunk cc: 2048 target points -> B-role fragments ----
        const float* tb = tpts + ((size_t)b * NPTS + (size_t)cc * 2048) * 3;
        #pragma unroll
        for (int k = 0; k < 8; ++k) {
            const int pi = k * 256 + tid;      // point within chunk
            const float x = tb[pi * 3 + 0];
            const float y = tb[pi * 3 + 1];
            const float z = tb[pi * 3 + 2];
            const float S = fmaf(x, x, fmaf(y, y, z * z));
            const unsigned short Xh = bf16_rne(x), Xl = bf16_rne(x - bf16f(Xh));
            const unsigned short Yh = bf16_rne(y), Yl = bf16_rne(y - bf16f(Yh));
            const unsigned short Zh = bf16_rne(z), Zl = bf16_rne(z - bf16f(Zh));
            const unsigned short Sh = bf16_rne(S), Sl = bf16_rne(S - bf16f(Sh));
            FragCast f0, f1;
            f0.v[0] = (short)Xh; f0.v[1] = (short)Xl; f0.v[2] = (short)Xh; f0.v[3] = (short)Yh;
            f0.v[4] = (short)Yl; f0.v[5] = (short)Yh; f0.v[6] = (short)Zh; f0.v[7] = (short)Zl;
            f1.v[0] = (short)Zh; f1.v[1] = (short)Sh; f1.v[2] = (short)Sl; f1.v[3] = (short)one;
            f1.v[4] = (short)one; f1.v[5] = 0;        f1.v[6] = 0;         f1.v[7] = 0;
            const int t  = pi >> 5;
            const int c2 = pi & 31;
            lds[t * 64 + c2]      = f0.u;   // g=0 chunk for point c2
            lds[t * 64 + 32 + c2] = f1.u;   // g=1 chunk
        }
        __syncthreads();

        // ---- Inner MFMA loop (identical op order to R6) ----
        #pragma unroll 2
        for (int t = 0; t < 64; t += 2) {
            FragCast ta, tb2;
            ta.u  = lds[(t + 0) * 64 + l];
            tb2.u = lds[(t + 1) * 64 + l];
            // 1 ds_read pair feeds 4 MFMAs (2 strips x 2 tiles)
            f32x16 a0 = __builtin_amdgcn_mfma_f32_32x32x16_bf16(af0, ta.v,  vzero, 0, 0, 0);
            f32x16 a1 = __builtin_amdgcn_mfma_f32_32x32x16_bf16(af0, tb2.v, vzero, 0, 0, 0);
            f32x16 b0 = __builtin_amdgcn_mfma_f32_32x32x16_bf16(af1, ta.v,  vzero, 0, 0, 0);
            f32x16 b1 = __builtin_amdgcn_mfma_f32_32x32x16_bf16(af1, tb2.v, vzero, 0, 0, 0);
            #pragma unroll
            for (int i = 0; i < 16; ++i) {
                rm0[i] = fminf(fminf(rm0[i], a0[i]), a1[i]);   // -> v_min3_f32
                rm1[i] = fminf(fminf(rm1[i], b0[i]), b1[i]);
            }
        }
    }

    // Cross-lane min over the 32 columns (within each 32-lane half; halves
    // hold disjoint row sets per C layout row=(i&3)+8*(i>>2)+4*g).
    #pragma unroll
    for (int m = 1; m <= 16; m <<= 1) {
        #pragma unroll
        for (int i = 0; i < 16; ++i) {
            rm0[i] = fminf(rm0[i], __shfl_xor(rm0[i], m, 64));
            rm1[i] = fminf(rm1[i], __shfl_xor(rm1[i], m, 64));
        }
    }

    // Clamp (min of clamped == clamp of min) and sum this wave's 64 rows.
    float s0 = 0.0f, s1 = 0.0f;
    #pragma unroll
    for (int i = 0; i < 16; ++i) {
        s0 += fmaxf(rm0[i], 0.0f);
        s1 += fmaxf(rm1[i], 0.0f);
    }
    s0 += __shfl_xor(s0, 32, 64);
    s1 += __shfl_xor(s1, 32, 64);
    const float s = s0 + s1;

    __shared__ float wsum[4];
    if (l == 0) wsum[wid] = s;
    __syncthreads();
    if (tid == 0)
        partials[orig] = wsum[0] + wsum[1] + wsum[2] + wsum[3];
}

// ---------------- Pass 2: single-block final sum -> mean -------------------
__global__ __launch_bounds__(256) void final_kernel(
    const float* __restrict__ partials, float* __restrict__ out)
{
    const int t = (int)threadIdx.x;
    float v = partials[t] + partials[t + 256];

    #pragma unroll
    for (int off = 32; off >= 1; off >>= 1)
        v += __shfl_down(v, off, 64);

    __shared__ float wsum[4];
    const int lane = t & 63;
    const int wid  = t >> 6;
    if (lane == 0) wsum[wid] = v;
    __syncthreads();
    if (t == 0)
        out[0] = (wsum[0] + wsum[1] + wsum[2] + wsum[3]) * (1.0f / (float)NQ_TOTAL);
}

extern "C" void kernel_launch(void* const* d_in, const int* in_sizes, int n_in,
                              void* d_out, int out_size, void* d_ws, size_t ws_size,
                              hipStream_t stream) {
    const float* xyz1 = (const float*)d_in[0];
    const float* xyz2 = (const float*)d_in[1];
    float* out = (float*)d_out;
    float* partials = (float*)d_ws;   // 512 floats

    chamfer_fused_kernel<<<512, 256, 0, stream>>>(xyz1, xyz2, partials);
    final_kernel<<<1, 256, 0, stream>>>(partials, out);
}